// Round 9
// baseline (686.077 us; speedup 1.0000x reference)
//
#include <hip/hip_runtime.h>
#include <hip/hip_bf16.h>
#include <hip/hip_fp16.h>

typedef __bf16 bf16x8 __attribute__((ext_vector_type(8)));
typedef float  f32x4  __attribute__((ext_vector_type(4)));
typedef float  f32x16 __attribute__((ext_vector_type(16)));

#define C_H 56
#define C_W 56
#define C_C 256
#define C_F 256
#define C_B 64
#define N_PIX (C_B * C_H * C_W)          // 200704
#define WB_ELEMS (9 * C_C * C_F)         // 589824
#define WB_BYTES (WB_ELEMS * 2)          // 1179648
#define XQ_OFF WB_BYTES                  // padded-x right after weights
#define XQ_PIX (C_B * 58 * 58)           // 215296 padded pixels
#define XQ_BYTES ((size_t)XQ_PIX * 512)  // 110,231,552
#define X_ELEMS (N_PIX * C_C)            // 51380224

#define GLOAD_LDS16(g, l)                                                   \
    __builtin_amdgcn_global_load_lds(                                        \
        (const __attribute__((address_space(1))) void*)(g),                  \
        (__attribute__((address_space(3))) void*)(l), 16, 0, 0)

// ---- prep: binarize weights into direct-load fragment layout ----
// w[s][c][f] fp32 -> wq[s][cc][kk][half][f][8j] bf16  (c = cc*32+kk*16+half*8+j)
__global__ void prep_w2_kernel(const float* __restrict__ w, __bf16* __restrict__ wq) {
    int idx = blockIdx.x * 256 + threadIdx.x;       // 589824
    int f = idx & 255;
    int c = (idx >> 8) & 255;
    int s = idx >> 16;
    float wf = w[idx];
    float v = __half2float(__float2half(wf));       // fp16 round-trip
    float sgn = (v > 0.f) ? 1.f : ((v < 0.f) ? -1.f : 0.f);
    int cc = c >> 5, r5 = c & 31;
    int kk = r5 >> 4, half = (r5 >> 3) & 1, j = r5 & 7;
    int off = (((s * 8 + cc) * 2 + kk) * 2 + half) * 2048 + f * 8 + j;
    wq[off] = (__bf16)sgn;
}

// ---- prep: zero the pad ring of xq ----
__global__ void border_zero_kernel(float* __restrict__ xq) {
    int idx = blockIdx.x * 256 + threadIdx.x;       // 466944 total f32x4 writes
    int q = idx & 31;                                // 32 x 16B = 512B per pixel
    int pe = idx >> 5;                               // 0..14591
    int b = pe / 228;
    int e = pe - b * 228;
    int y, x;
    if (e < 58)       { y = 0;       x = e; }
    else if (e < 116) { y = 57;      x = e - 58; }
    else if (e < 172) { y = e - 115; x = 0; }
    else              { y = e - 171; x = 57; }
    f32x4* p = reinterpret_cast<f32x4*>(xq) + ((size_t)(b * 3364 + y * 58 + x) * 32 + q);
    *p = (f32x4){0.f, 0.f, 0.f, 0.f};
}

// ---- prep: x fp32 -> bf16 into padded [b][58][58][256] layout ----
__global__ void prep_x_pad_kernel(const float* __restrict__ x, __bf16* __restrict__ xq) {
    int i = blockIdx.x * 256 + threadIdx.x;          // X_ELEMS/8 threads
    int px = i >> 5;                                 // interior pixel
    int c8 = i & 31;
    int b = px / 3136;
    int rem = px - b * 3136;
    int y = rem / 56;
    int x2 = rem - y * 56;
    const f32x4* p = reinterpret_cast<const f32x4*>(x) + (size_t)i * 2;
    f32x4 a = p[0], bb = p[1];
    bf16x8 o;
    o[0] = (__bf16)a[0];  o[1] = (__bf16)a[1];  o[2] = (__bf16)a[2];  o[3] = (__bf16)a[3];
    o[4] = (__bf16)bb[0]; o[5] = (__bf16)bb[1]; o[6] = (__bf16)bb[2]; o[7] = (__bf16)bb[3];
    size_t dst = (size_t)(b * 3364 + (y + 1) * 58 + (x2 + 1)) * 32 + c8;
    reinterpret_cast<bf16x8*>(xq)[dst] = o;
}

// padded-space shift offset for tap s, in bytes
#define DOFFB(S) ((((S) / 3 - 1) * 58 + ((S) % 3 - 1)) * 512)

// ---- main conv: 256x128 tile, 4 waves (2Mx2N, 128x64/wave), 32x32x16 MFMA ----
// A: LDS-staged (3 bufs x 16KB, lookahead +2, counted vmcnt(4), 1 barrier/step)
// B: direct-from-L2 register prefetch (1 step ahead), fragment-major layout.
// K order: kt = cc*9 + s (s fastest). Swizzle on A: chunk ^= (row>>1)&3.
// R9: occupancy 2 -> 3 blocks/CU (LDS 3x48=144KB fits; VGPR cap ~168 >= 128).
__global__ __launch_bounds__(256, 3) void conv_k32_kernel(
    const char* __restrict__ xq,       // padded bf16 x, 512B rows
    const char* __restrict__ wqp,      // fragment-major bf16 weights
    float* __restrict__ out) {

    __shared__ __align__(16) char sm[3][16384];

    // XCD-chunked bijective swizzle: 1568 = 8 * 196
    const int nbid = (blockIdx.x & 7) * 196 + (blockIdx.x >> 3);
    const int mtile = nbid >> 1;
    const int ftile = nbid & 1;
    const long m0 = (long)mtile * 256;
    const int fb = ftile * 128;

    const int tid  = threadIdx.x;
    const int lane = tid & 63;
    const int w    = tid >> 6;          // 0..3
    const int l31  = lane & 31;
    const int half = lane >> 5;         // 0..1
    const int wm   = w >> 1;            // 0..1 (M half: 128 rows)
    const int wn   = w & 1;             // 0..1 (N half: 64 cols)

    // A fragment read addressing (swizzled)
    const int x31 = (l31 >> 1) & 3;
    const int colA0 = ((half ^ x31) << 4);
    const int colA1 = colA0 ^ 32;
    const int rdAbase = (wm * 128 + l31) * 64;

    // B direct-load per-lane base
    const int BL = (fb + wn * 64 + l31) * 16 + half * 4096;

    // A staging: source swizzle + padded pixel offsets for 4 rows
    const int sw = ((lane & 3) ^ ((lane >> 3) & 3)) << 4;
    int P[4];
    int ldst[4];
#pragma unroll
    for (int i = 0; i < 4; ++i) {
        int r = ((i * 4 + w) << 4) + (lane >> 2);    // 0..255
        int p = (int)m0 + r;
        int b = p / 3136;
        int rem = p - b * 3136;
        int y = rem / 56;
        int xx = rem - y * 56;
        P[i] = (b * 3364 + (y + 1) * 58 + (xx + 1)) * 512 + sw;
        ldst[i] = (i * 4 + w) * 1024 + lane * 16;
    }

    f32x16 acc[4][2];
#pragma unroll
    for (int i = 0; i < 4; ++i)
#pragma unroll
        for (int j = 0; j < 2; ++j)
            acc[i][j] = (f32x16)(0.f);

    bf16x8 Bp0[2][2], Bp1[2][2];

#define ASTAGE(S2, SB2, CA2)                                                 \
    {                                                                        \
        _Pragma("unroll")                                                    \
        for (int i = 0; i < 4; ++i)                                          \
            GLOAD_LDS16(xq + (P[i] + DOFFB(S2) + (CA2)),                     \
                        &sm[(SB2)][0] + ldst[i]);                            \
    }

#define BPREF(DST, S1, CB1)                                                  \
    {                                                                        \
        _Pragma("unroll")                                                    \
        for (int nt = 0; nt < 2; ++nt)                                       \
            _Pragma("unroll")                                                \
            for (int kk = 0; kk < 2; ++kk)                                   \
                DST[nt][kk] = *reinterpret_cast<const bf16x8*>(              \
                    wqp + (BL + nt * 512 + (S1) * 131072 + kk * 8192 + (CB1)));\
    }

#define STEP(BUF, CONS, LOAD, S1, CB1, S2, SB2, CA2, DOSTAGE, WVM)           \
    {                                                                        \
        asm volatile("s_waitcnt vmcnt(" WVM ")" ::: "memory");               \
        __builtin_amdgcn_s_barrier();                                        \
        const char* Lb = &sm[(BUF)][0];                                      \
        bf16x8 Af[4][2];                                                     \
        _Pragma("unroll")                                                    \
        for (int mt = 0; mt < 4; ++mt) {                                     \
            Af[mt][0] = *reinterpret_cast<const bf16x8*>(Lb + rdAbase + mt * 2048 + colA0); \
            Af[mt][1] = *reinterpret_cast<const bf16x8*>(Lb + rdAbase + mt * 2048 + colA1); \
        }                                                                    \
        BPREF(LOAD, S1, CB1);                                                \
        if (DOSTAGE) ASTAGE(S2, SB2, CA2);                                   \
        _Pragma("unroll")                                                    \
        for (int mt = 0; mt < 4; ++mt)                                       \
            _Pragma("unroll")                                                \
            for (int nt = 0; nt < 2; ++nt)                                   \
                _Pragma("unroll")                                            \
                for (int kk = 0; kk < 2; ++kk)                               \
                    acc[mt][nt] = __builtin_amdgcn_mfma_f32_32x32x16_bf16(   \
                        Af[mt][kk], CONS[nt][kk], acc[mt][nt], 0, 0, 0);     \
    }

// 9 steps of one cc; PA/PB are consume/load role arrays for even S
#define NINE(CA, CB, PA, PB, DS7, DS8, WV8)                                  \
    STEP(0, PA, PB, 1, (CB),         2, 2, (CA),      true,  "4")            \
    STEP(1, PB, PA, 2, (CB),         3, 0, (CA),      true,  "4")            \
    STEP(2, PA, PB, 3, (CB),         4, 1, (CA),      true,  "4")            \
    STEP(0, PB, PA, 4, (CB),         5, 2, (CA),      true,  "4")            \
    STEP(1, PA, PB, 5, (CB),         6, 0, (CA),      true,  "4")            \
    STEP(2, PB, PA, 6, (CB),         7, 1, (CA),      true,  "4")            \
    STEP(0, PA, PB, 7, (CB),         8, 2, (CA),      true,  "4")            \
    STEP(1, PB, PA, 8, (CB),         0, 0, (CA) + 64, DS7,   "4")            \
    STEP(2, PA, PB, 0, (CB) + 16384, 1, 1, (CA) + 64, DS8,   WV8)

    // ---- prologue: A(0)->buf0, A(1)->buf1, B(0)->Bp0 ----
    ASTAGE(0, 0, 0);
    { // stage(1): s=1, cc=0 -> buf1
        _Pragma("unroll")
        for (int i = 0; i < 4; ++i)
            GLOAD_LDS16(xq + (P[i] + DOFFB(1)), &sm[1][0] + ldst[i]);
    }
    BPREF(Bp0, 0, 0);
    asm volatile("s_waitcnt vmcnt(0)" ::: "memory");
    __builtin_amdgcn_s_barrier();

    // ---- main: ccp = 0..2 (cc pairs 0-5), all staging on ----
    for (int ccp = 0; ccp < 3; ++ccp) {
        const int a0 = ccp * 128;           // cc*64 for even cc
        const int b0 = ccp * 32768;         // cc*16384 for even cc
        NINE(a0,      b0,         Bp0, Bp1, true, true, "4")
        NINE(a0 + 64, b0 + 16384, Bp1, Bp0, true, true, "4")
    }
    // ---- peeled ccp=3 (cc 6,7): last two steps don't stage; last waits 0 ----
    {
        const int a0 = 384;                 // 3*128
        const int b0 = 98304;               // 3*32768
        NINE(a0,      b0,         Bp0, Bp1, true,  true,  "4")
        NINE(a0 + 64, b0 + 16384, Bp1, Bp0, false, false, "0")
    }

#undef NINE
#undef STEP
#undef BPREF
#undef ASTAGE

    // ---- epilogue: D col(f)=lane&31, row=(j&3)+8*(j>>2)+4*half ----
#pragma unroll
    for (int mt = 0; mt < 4; ++mt) {
#pragma unroll
        for (int nt = 0; nt < 2; ++nt) {
#pragma unroll
            for (int j = 0; j < 16; ++j) {
                long row = m0 + wm * 128 + mt * 32 + (j & 3) + 8 * (j >> 2) + 4 * half;
                int col = fb + wn * 64 + nt * 32 + l31;
                out[row * C_F + col] = acc[mt][nt][j];
            }
        }
    }
}

// ---- fallback path (small ws): direct-from-global, fp32 loads ----
__global__ void prep_w_kernel(const float* __restrict__ w, __bf16* __restrict__ wbT) {
    int idx = blockIdx.x * 256 + threadIdx.x;
    int f = idx & 255;
    int c = (idx >> 8) & 255;
    int s = idx >> 16;
    float wf = w[idx];
    float v = __half2float(__float2half(wf));
    float sgn = (v > 0.f) ? 1.f : ((v < 0.f) ? -1.f : 0.f);
    wbT[(s << 16) + (f << 8) + c] = (__bf16)sgn;
}

__global__ void zero_kernel(float* __restrict__ z) {
    z[threadIdx.x] = 0.f;
}

__global__ __launch_bounds__(256) void conv_fallback_kernel(
    const float* __restrict__ xf,
    const __bf16* __restrict__ wbT, const char* __restrict__ zbuf,
    float* __restrict__ out) {

    const int lane = threadIdx.x & 63;
    const int wave = threadIdx.x >> 6;
    const int l15  = lane & 15;
    const int g    = lane >> 4;
    const int goff = g * 8;
    const long m0  = (long)blockIdx.x * 64;
    const int fbase = wave * 64;

    int ry[4], rx[4];
    long rbase[4];
#pragma unroll
    for (int ai = 0; ai < 4; ++ai) {
        int rr = (int)m0 + ai * 16 + l15;
        int b = rr / 3136;
        int rem = rr - b * 3136;
        int yy2 = rem / 56;
        ry[ai] = yy2;
        rx[ai] = rem - yy2 * 56;
        rbase[ai] = (long)rr * C_C;
    }

    f32x4 acc[4][4];
#pragma unroll
    for (int i = 0; i < 4; ++i)
#pragma unroll
        for (int j = 0; j < 4; ++j)
            acc[i][j] = (f32x4){0.f, 0.f, 0.f, 0.f};

    for (int s = 0; s < 9; ++s) {
        const int dy = s / 3 - 1;
        const int dx = (s - (s / 3) * 3) - 1;
        const float* af[4];
#pragma unroll
        for (int ai = 0; ai < 4; ++ai) {
            bool v = ((unsigned)(ry[ai] + dy) < 56u) & ((unsigned)(rx[ai] + dx) < 56u);
            long off = rbase[ai] + (long)(dy * C_W + dx) * C_C + goff;
            af[ai] = v ? (xf + off) : ((const float*)zbuf + goff);
        }
        const __bf16* bp = wbT + ((size_t)(s * 256 + fbase + l15)) * C_C + goff;

#pragma unroll
        for (int cc = 0; cc < 8; ++cc) {
            const int c0 = cc * 32;
            bf16x8 A[4], Bf[4];
#pragma unroll
            for (int ai = 0; ai < 4; ++ai) {
                const f32x4* p = reinterpret_cast<const f32x4*>(af[ai] + c0);
                f32x4 u = p[0], w2 = p[1];
                bf16x8 t;
                t[0] = (__bf16)u[0]; t[1] = (__bf16)u[1]; t[2] = (__bf16)u[2]; t[3] = (__bf16)u[3];
                t[4] = (__bf16)w2[0]; t[5] = (__bf16)w2[1]; t[6] = (__bf16)w2[2]; t[7] = (__bf16)w2[3];
                A[ai] = t;
            }
#pragma unroll
            for (int bj = 0; bj < 4; ++bj)
                Bf[bj] = *reinterpret_cast<const bf16x8*>(bp + bj * 16 * C_C + c0);
#pragma unroll
            for (int ai = 0; ai < 4; ++ai)
#pragma unroll
                for (int bj = 0; bj < 4; ++bj)
                    acc[ai][bj] = __builtin_amdgcn_mfma_f32_16x16x32_bf16(A[ai], Bf[bj], acc[ai][bj], 0, 0, 0);
        }
    }

#pragma unroll
    for (int ai = 0; ai < 4; ++ai) {
#pragma unroll
        for (int j = 0; j < 4; ++j) {
            long row = m0 + ai * 16 + g * 4 + j;
            float* op = out + row * C_F + fbase + l15;
#pragma unroll
            for (int bj = 0; bj < 4; ++bj)
                op[bj * 16] = acc[ai][bj][j];
        }
    }
}

extern "C" void kernel_launch(void* const* d_in, const int* in_sizes, int n_in,
                              void* d_out, int out_size, void* d_ws, size_t ws_size,
                              hipStream_t stream) {
    const float* x = (const float*)d_in[0];
    const float* w = (const float*)d_in[1];
    float* out = (float*)d_out;

    char* ws = (char*)d_ws;
    const bool big = ws_size >= (size_t)XQ_OFF + XQ_BYTES;

    if (big) {
        __bf16* wq = (__bf16*)ws;
        __bf16* xq = (__bf16*)(ws + XQ_OFF);
        prep_w2_kernel<<<WB_ELEMS / 256, 256, 0, stream>>>(w, wq);
        border_zero_kernel<<<1824, 256, 0, stream>>>((float*)xq);
        prep_x_pad_kernel<<<X_ELEMS / 8 / 256, 256, 0, stream>>>(x, xq);
        conv_k32_kernel<<<N_PIX / 256 * 2, 256, 0, stream>>>(
            (const char*)xq, (const char*)wq, out);
    } else {
        __bf16* wbT = (__bf16*)ws;
        char* zbuf = ws + WB_BYTES;
        prep_w_kernel<<<WB_ELEMS / 256, 256, 0, stream>>>(w, wbT);
        zero_kernel<<<1, 256, 0, stream>>>((float*)zbuf);
        conv_fallback_kernel<<<N_PIX / 64, 256, 0, stream>>>(x, wbT, zbuf, out);
    }
}

// Round 10
// 310.041 us; speedup vs baseline: 2.2129x; 2.2129x over previous
//
#include <hip/hip_runtime.h>
#include <hip/hip_bf16.h>
#include <hip/hip_fp16.h>

typedef __bf16 bf16x8 __attribute__((ext_vector_type(8)));
typedef float  f32x4  __attribute__((ext_vector_type(4)));
typedef float  f32x16 __attribute__((ext_vector_type(16)));

#define C_H 56
#define C_W 56
#define C_C 256
#define C_F 256
#define C_B 64
#define N_PIX (C_B * C_H * C_W)          // 200704
#define WB_ELEMS (9 * C_C * C_F)         // 589824
#define WB_BYTES (WB_ELEMS * 2)          // 1179648
#define XQ_OFF WB_BYTES                  // padded-x right after weights
#define XQ_PIX (C_B * 58 * 58)           // 215296 padded pixels
#define XQ_BYTES ((size_t)XQ_PIX * 512)  // 110,231,552
#define X_ELEMS (N_PIX * C_C)            // 51380224

#define GLOAD_LDS16(g, l)                                                   \
    __builtin_amdgcn_global_load_lds(                                        \
        (const __attribute__((address_space(1))) void*)(g),                  \
        (__attribute__((address_space(3))) void*)(l), 16, 0, 0)

// ---- prep: binarize weights into direct-load fragment layout ----
// w[s][c][f] fp32 -> wq[s][cc][kk][half][f][8j] bf16  (c = cc*32+kk*16+half*8+j)
__global__ void prep_w2_kernel(const float* __restrict__ w, __bf16* __restrict__ wq) {
    int idx = blockIdx.x * 256 + threadIdx.x;       // 589824
    int f = idx & 255;
    int c = (idx >> 8) & 255;
    int s = idx >> 16;
    float wf = w[idx];
    float v = __half2float(__float2half(wf));       // fp16 round-trip
    float sgn = (v > 0.f) ? 1.f : ((v < 0.f) ? -1.f : 0.f);
    int cc = c >> 5, r5 = c & 31;
    int kk = r5 >> 4, half = (r5 >> 3) & 1, j = r5 & 7;
    int off = (((s * 8 + cc) * 2 + kk) * 2 + half) * 2048 + f * 8 + j;
    wq[off] = (__bf16)sgn;
}

// ---- prep: zero the pad ring of xq ----
__global__ void border_zero_kernel(float* __restrict__ xq) {
    int idx = blockIdx.x * 256 + threadIdx.x;       // 466944 total f32x4 writes
    int q = idx & 31;                                // 32 x 16B = 512B per pixel
    int pe = idx >> 5;                               // 0..14591
    int b = pe / 228;
    int e = pe - b * 228;
    int y, x;
    if (e < 58)       { y = 0;       x = e; }
    else if (e < 116) { y = 57;      x = e - 58; }
    else if (e < 172) { y = e - 115; x = 0; }
    else              { y = e - 171; x = 57; }
    f32x4* p = reinterpret_cast<f32x4*>(xq) + ((size_t)(b * 3364 + y * 58 + x) * 32 + q);
    *p = (f32x4){0.f, 0.f, 0.f, 0.f};
}

// ---- prep: x fp32 -> bf16 into padded [b][58][58][256] layout ----
__global__ void prep_x_pad_kernel(const float* __restrict__ x, __bf16* __restrict__ xq) {
    int i = blockIdx.x * 256 + threadIdx.x;          // X_ELEMS/8 threads
    int px = i >> 5;                                 // interior pixel
    int c8 = i & 31;
    int b = px / 3136;
    int rem = px - b * 3136;
    int y = rem / 56;
    int x2 = rem - y * 56;
    const f32x4* p = reinterpret_cast<const f32x4*>(x) + (size_t)i * 2;
    f32x4 a = p[0], bb = p[1];
    bf16x8 o;
    o[0] = (__bf16)a[0];  o[1] = (__bf16)a[1];  o[2] = (__bf16)a[2];  o[3] = (__bf16)a[3];
    o[4] = (__bf16)bb[0]; o[5] = (__bf16)bb[1]; o[6] = (__bf16)bb[2]; o[7] = (__bf16)bb[3];
    size_t dst = (size_t)(b * 3364 + (y + 1) * 58 + (x2 + 1)) * 32 + c8;
    reinterpret_cast<bf16x8*>(xq)[dst] = o;
}

// padded-space shift offset for tap s, in bytes
#define DOFFB(S) ((((S) / 3 - 1) * 58 + ((S) % 3 - 1)) * 512)

// ---- main conv: 128x128 tile, 4 waves (2Mx2N, 64x64/wave), 32x32x16 MFMA ----
// acc = 2x2 f32x16 = 64 regs/wave -> ~145 total -> TRUE 3 blocks/CU (12 waves).
// A: LDS-staged (3 bufs x 8KB, lookahead +2, counted vmcnt(2), 1 barrier/step)
// B: direct-from-L2 register prefetch (1 step ahead), fragment-major layout.
// K order: kt = cc*9 + s (s fastest). Swizzle on A: chunk ^= (row>>1)&3.
__global__ __launch_bounds__(256, 3) void conv_k32_kernel(
    const char* __restrict__ xq,       // padded bf16 x, 512B rows
    const char* __restrict__ wqp,      // fragment-major bf16 weights
    float* __restrict__ out) {

    __shared__ __align__(16) char sm[3][8192];

    // XCD-chunked bijective swizzle: 3136 = 8 * 392
    const int nbid = (blockIdx.x & 7) * 392 + (blockIdx.x >> 3);
    const int mtile = nbid >> 1;
    const int ftile = nbid & 1;        // A-sharing pair adjacent on one XCD
    const long m0 = (long)mtile * 128;
    const int fb = ftile * 128;

    const int tid  = threadIdx.x;
    const int lane = tid & 63;
    const int w    = tid >> 6;          // 0..3
    const int l31  = lane & 31;
    const int half = lane >> 5;         // 0..1
    const int wm   = w >> 1;            // 0..1 (M half: 64 rows)
    const int wn   = w & 1;             // 0..1 (N half: 64 cols)

    // A fragment read addressing (swizzled): row = wm*64 + l31, 64B rows
    const int x31 = (l31 >> 1) & 3;
    const int colA0 = ((half ^ x31) << 4);          // kk=0 physical chunk
    const int colA1 = colA0 ^ 32;                   // kk=1
    const int rdAbase = (wm * 64 + l31) * 64;       // + mt*2048

    // B direct-load per-lane base: f = fb + wn*64 + nt*32 + l31
    const int BL = (fb + wn * 64 + l31) * 16 + half * 4096;   // + nt*512

    // A staging: 2 x gload_lds16/thread covers 128 rows x 64B
    const int sw = ((tid & 3) ^ ((tid >> 3) & 3)) << 4;   // inverse-swizzled src col
    int P[2];
#pragma unroll
    for (int i = 0; i < 2; ++i) {
        int r = (tid >> 2) + i * 64;                 // 0..127
        int p = (int)m0 + r;
        int b = p / 3136;
        int rem = p - b * 3136;
        int y = rem / 56;
        int xx = rem - y * 56;
        P[i] = (b * 3364 + (y + 1) * 58 + (xx + 1)) * 512 + sw;
    }

    f32x16 acc[2][2];
#pragma unroll
    for (int i = 0; i < 2; ++i)
#pragma unroll
        for (int j = 0; j < 2; ++j)
            acc[i][j] = (f32x16)(0.f);

    bf16x8 Bp0[2][2], Bp1[2][2];

#define ASTAGE(S2, SB2, CA2)                                                 \
    {                                                                        \
        _Pragma("unroll")                                                    \
        for (int i = 0; i < 2; ++i)                                          \
            GLOAD_LDS16(xq + (P[i] + DOFFB(S2) + (CA2)),                     \
                        &sm[(SB2)][0] + i * 4096 + tid * 16);                \
    }

#define BPREF(DST, S1, CB1)                                                  \
    {                                                                        \
        _Pragma("unroll")                                                    \
        for (int nt = 0; nt < 2; ++nt)                                       \
            _Pragma("unroll")                                                \
            for (int kk = 0; kk < 2; ++kk)                                   \
                DST[nt][kk] = *reinterpret_cast<const bf16x8*>(              \
                    wqp + (BL + nt * 512 + (S1) * 131072 + kk * 8192 + (CB1)));\
    }

#define STEP(BUF, CONS, LOAD, S1, CB1, S2, SB2, CA2, DOSTAGE, WVM)           \
    {                                                                        \
        asm volatile("s_waitcnt vmcnt(" WVM ")" ::: "memory");               \
        __builtin_amdgcn_s_barrier();                                        \
        const char* Lb = &sm[(BUF)][0];                                      \
        bf16x8 Af[2][2];                                                     \
        _Pragma("unroll")                                                    \
        for (int mt = 0; mt < 2; ++mt) {                                     \
            Af[mt][0] = *reinterpret_cast<const bf16x8*>(Lb + rdAbase + mt * 2048 + colA0); \
            Af[mt][1] = *reinterpret_cast<const bf16x8*>(Lb + rdAbase + mt * 2048 + colA1); \
        }                                                                    \
        BPREF(LOAD, S1, CB1);                                                \
        if (DOSTAGE) ASTAGE(S2, SB2, CA2);                                   \
        _Pragma("unroll")                                                    \
        for (int mt = 0; mt < 2; ++mt)                                       \
            _Pragma("unroll")                                                \
            for (int nt = 0; nt < 2; ++nt)                                   \
                _Pragma("unroll")                                            \
                for (int kk = 0; kk < 2; ++kk)                               \
                    acc[mt][nt] = __builtin_amdgcn_mfma_f32_32x32x16_bf16(   \
                        Af[mt][kk], CONS[nt][kk], acc[mt][nt], 0, 0, 0);     \
    }

// 9 steps of one cc; buffers follow t%3 (9%3==0 so each NINE starts at buf0)
#define NINE(CA, CB, PA, PB, DS7, DS8, WV8)                                  \
    STEP(0, PA, PB, 1, (CB),         2, 2, (CA),      true,  "2")            \
    STEP(1, PB, PA, 2, (CB),         3, 0, (CA),      true,  "2")            \
    STEP(2, PA, PB, 3, (CB),         4, 1, (CA),      true,  "2")            \
    STEP(0, PB, PA, 4, (CB),         5, 2, (CA),      true,  "2")            \
    STEP(1, PA, PB, 5, (CB),         6, 0, (CA),      true,  "2")            \
    STEP(2, PB, PA, 6, (CB),         7, 1, (CA),      true,  "2")            \
    STEP(0, PA, PB, 7, (CB),         8, 2, (CA),      true,  "2")            \
    STEP(1, PB, PA, 8, (CB),         0, 0, (CA) + 64, DS7,   "2")            \
    STEP(2, PA, PB, 0, (CB) + 16384, 1, 1, (CA) + 64, DS8,   WV8)

    // ---- prologue: B(0) first (so vmcnt(2) drains it), then A(0), A(1) ----
    BPREF(Bp0, 0, 0);
    ASTAGE(0, 0, 0);
    ASTAGE(1, 1, 0);

    // ---- main: ccp = 0..2 (cc 0-5), all staging on ----
    for (int ccp = 0; ccp < 3; ++ccp) {
        const int a0 = ccp * 128;           // cc*64 for even cc
        const int b0 = ccp * 32768;         // cc*16384 for even cc
        NINE(a0,      b0,         Bp0, Bp1, true, true, "2")
        NINE(a0 + 64, b0 + 16384, Bp1, Bp0, true, true, "2")
    }
    // ---- peeled cc 6,7: last two steps don't stage; last waits 0 ----
    {
        NINE(384, 98304,  Bp0, Bp1, true,  true,  "2")
        NINE(448, 114688, Bp1, Bp0, false, false, "0")
    }

#undef NINE
#undef STEP
#undef BPREF
#undef ASTAGE

    // ---- epilogue: D col(f)=lane&31, row=(j&3)+8*(j>>2)+4*half ----
#pragma unroll
    for (int mt = 0; mt < 2; ++mt) {
#pragma unroll
        for (int nt = 0; nt < 2; ++nt) {
#pragma unroll
            for (int j = 0; j < 16; ++j) {
                long row = m0 + wm * 64 + mt * 32 + (j & 3) + 8 * (j >> 2) + 4 * half;
                int col = fb + wn * 64 + nt * 32 + l31;
                out[row * C_F + col] = acc[mt][nt][j];
            }
        }
    }
}

// ---- fallback path (small ws): direct-from-global, fp32 loads ----
__global__ void prep_w_kernel(const float* __restrict__ w, __bf16* __restrict__ wbT) {
    int idx = blockIdx.x * 256 + threadIdx.x;
    int f = idx & 255;
    int c = (idx >> 8) & 255;
    int s = idx >> 16;
    float wf = w[idx];
    float v = __half2float(__float2half(wf));
    float sgn = (v > 0.f) ? 1.f : ((v < 0.f) ? -1.f : 0.f);
    wbT[(s << 16) + (f << 8) + c] = (__bf16)sgn;
}

__global__ void zero_kernel(float* __restrict__ z) {
    z[threadIdx.x] = 0.f;
}

__global__ __launch_bounds__(256) void conv_fallback_kernel(
    const float* __restrict__ xf,
    const __bf16* __restrict__ wbT, const char* __restrict__ zbuf,
    float* __restrict__ out) {

    const int lane = threadIdx.x & 63;
    const int wave = threadIdx.x >> 6;
    const int l15  = lane & 15;
    const int g    = lane >> 4;
    const int goff = g * 8;
    const long m0  = (long)blockIdx.x * 64;
    const int fbase = wave * 64;

    int ry[4], rx[4];
    long rbase[4];
#pragma unroll
    for (int ai = 0; ai < 4; ++ai) {
        int rr = (int)m0 + ai * 16 + l15;
        int b = rr / 3136;
        int rem = rr - b * 3136;
        int yy2 = rem / 56;
        ry[ai] = yy2;
        rx[ai] = rem - yy2 * 56;
        rbase[ai] = (long)rr * C_C;
    }

    f32x4 acc[4][4];
#pragma unroll
    for (int i = 0; i < 4; ++i)
#pragma unroll
        for (int j = 0; j < 4; ++j)
            acc[i][j] = (f32x4){0.f, 0.f, 0.f, 0.f};

    for (int s = 0; s < 9; ++s) {
        const int dy = s / 3 - 1;
        const int dx = (s - (s / 3) * 3) - 1;
        const float* af[4];
#pragma unroll
        for (int ai = 0; ai < 4; ++ai) {
            bool v = ((unsigned)(ry[ai] + dy) < 56u) & ((unsigned)(rx[ai] + dx) < 56u);
            long off = rbase[ai] + (long)(dy * C_W + dx) * C_C + goff;
            af[ai] = v ? (xf + off) : ((const float*)zbuf + goff);
        }
        const __bf16* bp = wbT + ((size_t)(s * 256 + fbase + l15)) * C_C + goff;

#pragma unroll
        for (int cc = 0; cc < 8; ++cc) {
            const int c0 = cc * 32;
            bf16x8 A[4], Bf[4];
#pragma unroll
            for (int ai = 0; ai < 4; ++ai) {
                const f32x4* p = reinterpret_cast<const f32x4*>(af[ai] + c0);
                f32x4 u = p[0], w2 = p[1];
                bf16x8 t;
                t[0] = (__bf16)u[0]; t[1] = (__bf16)u[1]; t[2] = (__bf16)u[2]; t[3] = (__bf16)u[3];
                t[4] = (__bf16)w2[0]; t[5] = (__bf16)w2[1]; t[6] = (__bf16)w2[2]; t[7] = (__bf16)w2[3];
                A[ai] = t;
            }
#pragma unroll
            for (int bj = 0; bj < 4; ++bj)
                Bf[bj] = *reinterpret_cast<const bf16x8*>(bp + bj * 16 * C_C + c0);
#pragma unroll
            for (int ai = 0; ai < 4; ++ai)
#pragma unroll
                for (int bj = 0; bj < 4; ++bj)
                    acc[ai][bj] = __builtin_amdgcn_mfma_f32_16x16x32_bf16(A[ai], Bf[bj], acc[ai][bj], 0, 0, 0);
        }
    }

#pragma unroll
    for (int ai = 0; ai < 4; ++ai) {
#pragma unroll
        for (int j = 0; j < 4; ++j) {
            long row = m0 + ai * 16 + g * 4 + j;
            float* op = out + row * C_F + fbase + l15;
#pragma unroll
            for (int bj = 0; bj < 4; ++bj)
                op[bj * 16] = acc[ai][bj][j];
        }
    }
}

extern "C" void kernel_launch(void* const* d_in, const int* in_sizes, int n_in,
                              void* d_out, int out_size, void* d_ws, size_t ws_size,
                              hipStream_t stream) {
    const float* x = (const float*)d_in[0];
    const float* w = (const float*)d_in[1];
    float* out = (float*)d_out;

    char* ws = (char*)d_ws;
    const bool big = ws_size >= (size_t)XQ_OFF + XQ_BYTES;

    if (big) {
        __bf16* wq = (__bf16*)ws;
        __bf16* xq = (__bf16*)(ws + XQ_OFF);
        prep_w2_kernel<<<WB_ELEMS / 256, 256, 0, stream>>>(w, wq);
        border_zero_kernel<<<1824, 256, 0, stream>>>((float*)xq);
        prep_x_pad_kernel<<<X_ELEMS / 8 / 256, 256, 0, stream>>>(x, xq);
        conv_k32_kernel<<<N_PIX / 128 * 2, 256, 0, stream>>>(
            (const char*)xq, (const char*)wq, out);
    } else {
        __bf16* wbT = (__bf16*)ws;
        char* zbuf = ws + WB_BYTES;
        prep_w_kernel<<<WB_ELEMS / 256, 256, 0, stream>>>(w, wbT);
        zero_kernel<<<1, 256, 0, stream>>>((float*)zbuf);
        conv_fallback_kernel<<<N_PIX / 64, 256, 0, stream>>>(x, wbT, zbuf, out);
    }
}